// Round 10
// baseline (640.443 us; speedup 1.0000x reference)
//
#include <hip/hip_runtime.h>
#include <hip/hip_bf16.h>
#include <math.h>

#define CCH 256      // channels
#define MT  32       // points per block (halved: LDS 33.8KB -> 4 blocks/CU)
#define ROWE 264     // padded LDS row (bf16): 528 B stride
#define TPB 512

typedef __attribute__((ext_vector_type(8))) short short8;
typedef __attribute__((ext_vector_type(4))) float f32x4;
typedef __attribute__((ext_vector_type(2))) unsigned int uint2v;

// Module-scope device scratch: transposed bf16 weights (no d_ws dependency).
__device__ unsigned short g_T0[CCH * CCH];   // T0[n*256+k] = bf16(W_h0[k][n])
__device__ unsigned short g_T1[CCH * CCH];   // T1[n*256+k] = bf16(W_h1[k][n])
__device__ unsigned short g_Wo[16 * CCH];    // Wo[j][k] = bf16(W_out[k][j]), j<3 else 0

__device__ __forceinline__ unsigned short f2bf(float f) {
  unsigned u = __float_as_uint(f);
  u += 0x7fffu + ((u >> 16) & 1u);   // RNE
  return (unsigned short)(u >> 16);
}

// pack 2 relu'd floats to 2 bf16 in one instr (RNE)
__device__ __forceinline__ unsigned cvtpk(float lo, float hi) {
  unsigned r;
  asm("v_cvt_pk_bf16_f32 %0, %1, %2" : "=v"(r) : "v"(lo), "v"(hi));
  return r;
}

__global__ void transpose_w(const float* __restrict__ W0,
                            const float* __restrict__ W1) {
  __shared__ float tile[32][33];
  const float* src = blockIdx.z ? W1 : W0;
  unsigned short* dst = blockIdx.z ? g_T1 : g_T0;
  const int tx = threadIdx.x, ty = threadIdx.y;       // 32 x 8
  const int k0 = blockIdx.y * 32, n0 = blockIdx.x * 32;
#pragma unroll
  for (int r = 0; r < 4; ++r)
    tile[ty + r * 8][tx] = src[(k0 + ty + r * 8) * CCH + n0 + tx];
  __syncthreads();
#pragma unroll
  for (int r = 0; r < 4; ++r) {
    const int n = n0 + ty + r * 8;
    dst[n * CCH + k0 + tx] = f2bf(tile[tx][ty + r * 8]);
  }
}

__global__ void prep_wo(const float* __restrict__ W_out) {
  const int k = threadIdx.x;   // 256 threads
#pragma unroll
  for (int j = 0; j < 16; ++j)
    g_Wo[j * CCH + k] = (j < 3) ? f2bf(W_out[k * 3 + j]) : (unsigned short)0;
}

// dst = relu(src @ W + b). Swapped operands (D = W^T h^T). Weights loaded
// in-loop (L1/L2-hot, imm-offset folded); TLP (8 waves/SIMD) hides latency.
__device__ __forceinline__ void layer_mfma(
    const unsigned short (*__restrict__ src)[ROWE],
    unsigned short (*__restrict__ dst)[ROWE],
    const unsigned short* __restrict__ Wt,
    const float* __restrict__ bias,
    int wv, int l16, int lk8) {
  f32x4 acc[2][2];
#pragma unroll
  for (int mt = 0; mt < 2; ++mt)
#pragma unroll
    for (int nt = 0; nt < 2; ++nt)
      acc[mt][nt] = (f32x4){0.f, 0.f, 0.f, 0.f};

  const unsigned short* w0p = &Wt[(wv * 32 + l16) * CCH + lk8 * 8];
  const unsigned short* w1p = w0p + 16 * CCH;
  const unsigned short* a0p = &src[l16][lk8 * 8];

#pragma unroll
  for (int kk = 0; kk < 8; ++kk) {
    const int k = kk * 32;
    const short8 w0 = *(const short8*)&w0p[k];
    const short8 w1 = *(const short8*)&w1p[k];
    const short8 a0 = *(const short8*)&a0p[k];
    const short8 a1 = *(const short8*)&a0p[16 * ROWE + k];
    acc[0][0] = __builtin_amdgcn_mfma_f32_16x16x32_bf16(w0, a0, acc[0][0], 0, 0, 0);
    acc[0][1] = __builtin_amdgcn_mfma_f32_16x16x32_bf16(w1, a0, acc[0][1], 0, 0, 0);
    acc[1][0] = __builtin_amdgcn_mfma_f32_16x16x32_bf16(w0, a1, acc[1][0], 0, 0, 0);
    acc[1][1] = __builtin_amdgcn_mfma_f32_16x16x32_bf16(w1, a1, acc[1][1], 0, 0, 0);
  }

  // D[ch][pt]: pt = mt*16+l16, ch = wv*32 + nt*16 + lk8*4 + i
#pragma unroll
  for (int nt = 0; nt < 2; ++nt) {
    const int ch0 = wv * 32 + nt * 16 + lk8 * 4;
    const f32x4 bv = *(const f32x4*)&bias[ch0];
#pragma unroll
    for (int mt = 0; mt < 2; ++mt) {
      const int pt = mt * 16 + l16;
      uint2v pk;
      pk[0] = cvtpk(fmaxf(acc[mt][nt][0] + bv[0], 0.f),
                    fmaxf(acc[mt][nt][1] + bv[1], 0.f));
      pk[1] = cvtpk(fmaxf(acc[mt][nt][2] + bv[2], 0.f),
                    fmaxf(acc[mt][nt][3] + bv[3], 0.f));
      *(uint2v*)&dst[pt][ch0] = pk;   // 8B aligned
    }
  }
}

__global__ __launch_bounds__(TPB, 8) void nerf_fused(
    const float* __restrict__ uv,
    const float* __restrict__ W_in, const float* __restrict__ b_in,
    const float* __restrict__ b_h0, const float* __restrict__ b_h1,
    const float* __restrict__ b_out,
    float* __restrict__ out) {
  __shared__ unsigned short hA[MT][ROWE];
  __shared__ unsigned short hB[MT][ROWE];

  const int tid = threadIdx.x;
  const long n0 = (long)blockIdx.x * MT;
  const int wv = tid >> 6, ln = tid & 63;
  const int l16 = ln & 15, lk8 = ln >> 4;

  { // ---- layer 0: enc=[cos u, cos v, sin u, sin v] -> relu(enc@W_in+b_in)
    const int p = tid >> 4;            // 32 points, 16 threads each
    const int t15 = tid & 15;          // 16 channels per thread
    const float u = uv[(n0 + p) * 2 + 0];
    const float v = uv[(n0 + p) * 2 + 1];
    const float e0 = __cosf(u), e1 = __cosf(v), e2 = __sinf(u), e3 = __sinf(v);
#pragma unroll
    for (int j = 0; j < 4; ++j) {
      const int c = t15 * 4 + j * 64;
      const f32x4 w0 = *(const f32x4*)&W_in[0 * CCH + c];
      const f32x4 w1 = *(const f32x4*)&W_in[1 * CCH + c];
      const f32x4 w2 = *(const f32x4*)&W_in[2 * CCH + c];
      const f32x4 w3 = *(const f32x4*)&W_in[3 * CCH + c];
      const f32x4 bb = *(const f32x4*)&b_in[c];
      float x[4];
#pragma unroll
      for (int i = 0; i < 4; ++i)
        x[i] = fmaxf(bb[i] + e0 * w0[i] + e1 * w1[i] + e2 * w2[i] + e3 * w3[i], 0.f);
      uint2v pk;
      pk[0] = cvtpk(x[0], x[1]);
      pk[1] = cvtpk(x[2], x[3]);
      *(uint2v*)&hA[p][c] = pk;
    }
  }
  __syncthreads();

  layer_mfma(hA, hB, g_T0, b_h0, wv, l16, lk8);   // h0 -> h1
  __syncthreads();
  layer_mfma(hB, hA, g_T1, b_h1, wv, l16, lk8);   // h1 -> h2
  __syncthreads();

  // ---- output layer via MFMA: D = Wo(3x256, zero-pad to 16) @ h2^T ----
  if (wv < 2) {                                   // wave wv owns points wv*16..+15
    f32x4 oacc = (f32x4){0.f, 0.f, 0.f, 0.f};
#pragma unroll
    for (int kk = 0; kk < 8; ++kk) {
      const int k = kk * 32 + lk8 * 8;
      const short8 wo = *(const short8*)&g_Wo[l16 * CCH + k];
      const short8 hb = *(const short8*)&hA[wv * 16 + l16][k];
      oacc = __builtin_amdgcn_mfma_f32_16x16x32_bf16(wo, hb, oacc, 0, 0, 0);
    }
    // D: col=l16=point, row=lk8*4+i=output j; only lk8==0, j<3 are real
    if (lk8 == 0) {
      const long pt = n0 + wv * 16 + l16;
#pragma unroll
      for (int i = 0; i < 3; ++i)
        out[pt * 3 + i] = 1.f / (1.f + __expf(-(oacc[i] + b_out[i])));
    }
  }
}

extern "C" void kernel_launch(void* const* d_in, const int* in_sizes, int n_in,
                              void* d_out, int out_size, void* d_ws, size_t ws_size,
                              hipStream_t stream) {
  const float* uv    = (const float*)d_in[0];
  const float* W_in  = (const float*)d_in[1];
  const float* b_in  = (const float*)d_in[2];
  const float* W_h0  = (const float*)d_in[3];
  const float* b_h0  = (const float*)d_in[4];
  const float* W_h1  = (const float*)d_in[5];
  const float* b_h1  = (const float*)d_in[6];
  const float* W_out = (const float*)d_in[7];
  const float* b_out = (const float*)d_in[8];

  const int N = in_sizes[0] / 2;                    // 524288

  transpose_w<<<dim3(8, 8, 2), dim3(32, 8), 0, stream>>>(W_h0, W_h1);
  prep_wo<<<1, CCH, 0, stream>>>(W_out);
  nerf_fused<<<dim3(N / MT), dim3(TPB), 0, stream>>>(
      uv, W_in, b_in, b_h0, b_h1, b_out, (float*)d_out);
}

// Round 11
// 417.992 us; speedup vs baseline: 1.5322x; 1.5322x over previous
//
#include <hip/hip_runtime.h>
#include <hip/hip_bf16.h>
#include <math.h>

#define CCH 256      // channels
#define MT  64       // points per block
#define ROWE 264     // padded LDS row (bf16): 528 B stride
#define TPB 512

typedef __attribute__((ext_vector_type(8))) short short8;
typedef __attribute__((ext_vector_type(4))) float f32x4;
typedef __attribute__((ext_vector_type(2))) unsigned int uint2v;

// Module-scope device scratch: transposed bf16 weights.
__device__ unsigned short g_T0[CCH * CCH];   // T0[n*256+k] = bf16(W_h0[k][n])
__device__ unsigned short g_T1[CCH * CCH];   // T1[n*256+k] = bf16(W_h1[k][n])
__device__ unsigned short g_Wo[16 * CCH];    // Wo[j][k] = bf16(W_out[k][j]), j<3 else 0

__device__ __forceinline__ unsigned short f2bf(float f) {
  unsigned u = __float_as_uint(f);
  u += 0x7fffu + ((u >> 16) & 1u);   // RNE
  return (unsigned short)(u >> 16);
}
__device__ __forceinline__ unsigned cvtpk(float lo, float hi) {
  unsigned r;
  asm("v_cvt_pk_bf16_f32 %0, %1, %2" : "=v"(r) : "v"(lo), "v"(hi));
  return r;
}

__global__ void transpose_w(const float* __restrict__ W0,
                            const float* __restrict__ W1) {
  __shared__ float tile[32][33];
  const float* src = blockIdx.z ? W1 : W0;
  unsigned short* dst = blockIdx.z ? g_T1 : g_T0;
  const int tx = threadIdx.x, ty = threadIdx.y;       // 32 x 8
  const int k0 = blockIdx.y * 32, n0 = blockIdx.x * 32;
#pragma unroll
  for (int r = 0; r < 4; ++r)
    tile[ty + r * 8][tx] = src[(k0 + ty + r * 8) * CCH + n0 + tx];
  __syncthreads();
#pragma unroll
  for (int r = 0; r < 4; ++r) {
    const int n = n0 + ty + r * 8;
    dst[n * CCH + k0 + tx] = f2bf(tile[tx][ty + r * 8]);
  }
}

__global__ void prep_wo(const float* __restrict__ W_out) {
  const int k = threadIdx.x;   // 256 threads
#pragma unroll
  for (int j = 0; j < 16; ++j)
    g_Wo[j * CCH + k] = (j < 3) ? f2bf(W_out[k * 3 + j]) : (unsigned short)0;
}

// Async weight-fragment prefetch: asm load cannot be sunk/rematerialized.
#define WLOAD(dst, base, OFF)                                         \
  asm volatile("global_load_dwordx4 %0, %1, off offset:" #OFF        \
               : "=&v"(dst) : "v"(base))

// Counted wait; "+v" ties the fragment regs to the wait (def->use edge to MFMA).
#define WWAIT(VM, S)                                                  \
  asm volatile("s_waitcnt vmcnt(" #VM ")" : "+v"(r0[S]), "+v"(r1[S]))

// One K-step: 4 M-tiles x 2 N-tiles of MFMA consuming ring slot S.
#define MFMA4(SRC, KK, S)                                             \
  do {                                                                \
    _Pragma("unroll")                                                 \
    for (int mt = 0; mt < 4; ++mt) {                                  \
      const short8 a =                                                \
          *(const short8*)&SRC[mt * 16 + l16][(KK) * 32 + lk8 * 8];   \
      acc[mt][0] = __builtin_amdgcn_mfma_f32_16x16x32_bf16(           \
          r0[S], a, acc[mt][0], 0, 0, 0);                             \
      acc[mt][1] = __builtin_amdgcn_mfma_f32_16x16x32_bf16(           \
          r1[S], a, acc[mt][1], 0, 0, 0);                             \
    }                                                                 \
  } while (0)

__device__ __forceinline__ void epilogue_store(
    const f32x4 acc[4][2], unsigned short (*__restrict__ dst)[ROWE],
    f32x4 bA, f32x4 bB, int wv, int l16, int lk8) {
#pragma unroll
  for (int nt = 0; nt < 2; ++nt) {
    const int ch0 = wv * 32 + nt * 16 + lk8 * 4;
    const f32x4 bv = nt ? bB : bA;
#pragma unroll
    for (int mt = 0; mt < 4; ++mt) {
      uint2v pk;
      pk[0] = cvtpk(fmaxf(acc[mt][nt][0] + bv[0], 0.f),
                    fmaxf(acc[mt][nt][1] + bv[1], 0.f));
      pk[1] = cvtpk(fmaxf(acc[mt][nt][2] + bv[2], 0.f),
                    fmaxf(acc[mt][nt][3] + bv[3], 0.f));
      *(uint2v*)&dst[mt * 16 + l16][ch0] = pk;   // 8B aligned
    }
  }
}

__global__ __launch_bounds__(TPB, 4) void nerf_fused(
    const float* __restrict__ uv,
    const float* __restrict__ W_in, const float* __restrict__ b_in,
    const float* __restrict__ b_h0, const float* __restrict__ b_h1,
    const float* __restrict__ b_out,
    float* __restrict__ out) {
  __shared__ unsigned short hA[MT][ROWE];
  __shared__ unsigned short hB[MT][ROWE];

  const int tid = threadIdx.x;
  const long n0 = (long)blockIdx.x * MT;
  const int wv = tid >> 6, ln = tid & 63;
  const int l16 = ln & 15, lk8 = ln >> 4;

  // per-wave weight row bases (channel rows wv*32+l16 and +16)
  const unsigned short* p0 = &g_T0[(wv * 32 + l16) * CCH + lk8 * 8];
  const unsigned short* p1 = p0 + 16 * CCH;
  const unsigned short* q0 = &g_T1[(wv * 32 + l16) * CCH + lk8 * 8];
  const unsigned short* q1 = q0 + 16 * CCH;

  // bias preload to regs; pin so epilogues are VMEM-free (no vmcnt drains mid-ladder)
  const int chA = wv * 32 + lk8 * 4;
  f32x4 b0A = *(const f32x4*)&b_h0[chA];
  f32x4 b0B = *(const f32x4*)&b_h0[chA + 16];
  f32x4 b1A = *(const f32x4*)&b_h1[chA];
  f32x4 b1B = *(const f32x4*)&b_h1[chA + 16];
  asm volatile("" : "+v"(b0A), "+v"(b0B), "+v"(b1A), "+v"(b1B));

  // 4-deep ring: issue T0 chunks 0..3 before layer 0 (latency hidden under trig)
  short8 r0[4], r1[4];
  WLOAD(r0[0], p0, 0);   WLOAD(r1[0], p1, 0);
  WLOAD(r0[1], p0, 64);  WLOAD(r1[1], p1, 64);
  WLOAD(r0[2], p0, 128); WLOAD(r1[2], p1, 128);
  WLOAD(r0[3], p0, 192); WLOAD(r1[3], p1, 192);

  { // ---- layer 0: enc=[cos u, cos v, sin u, sin v] -> relu(enc@W_in+b_in)
    const int p = tid >> 3;
    const int t7 = tid & 7;
    const float u = uv[(n0 + p) * 2 + 0];
    const float v = uv[(n0 + p) * 2 + 1];
    const float e0 = __cosf(u), e1 = __cosf(v), e2 = __sinf(u), e3 = __sinf(v);
#pragma unroll
    for (int j = 0; j < 8; ++j) {
      const int c = t7 * 4 + j * 32;
      const f32x4 w0 = *(const f32x4*)&W_in[0 * CCH + c];
      const f32x4 w1 = *(const f32x4*)&W_in[1 * CCH + c];
      const f32x4 w2 = *(const f32x4*)&W_in[2 * CCH + c];
      const f32x4 w3 = *(const f32x4*)&W_in[3 * CCH + c];
      const f32x4 bb = *(const f32x4*)&b_in[c];
      float x[4];
#pragma unroll
      for (int i = 0; i < 4; ++i)
        x[i] = fmaxf(bb[i] + e0 * w0[i] + e1 * w1[i] + e2 * w2[i] + e3 * w3[i], 0.f);
      uint2v pk;
      pk[0] = cvtpk(x[0], x[1]);
      pk[1] = cvtpk(x[2], x[3]);
      *(uint2v*)&hA[p][c] = pk;
    }
  }
  __syncthreads();

  f32x4 acc[4][2];
#pragma unroll
  for (int mt = 0; mt < 4; ++mt)
#pragma unroll
    for (int nt = 0; nt < 2; ++nt)
      acc[mt][nt] = (f32x4){0.f, 0.f, 0.f, 0.f};

  // ---- gemm0: never-drain vmcnt ladder; T1 chunks issue during back half ----
  WWAIT(6, 0); MFMA4(hA, 0, 0); WLOAD(r0[0], p0, 256); WLOAD(r1[0], p1, 256);
  WWAIT(6, 1); MFMA4(hA, 1, 1); WLOAD(r0[1], p0, 320); WLOAD(r1[1], p1, 320);
  WWAIT(6, 2); MFMA4(hA, 2, 2); WLOAD(r0[2], p0, 384); WLOAD(r1[2], p1, 384);
  WWAIT(6, 3); MFMA4(hA, 3, 3); WLOAD(r0[3], p0, 448); WLOAD(r1[3], p1, 448);
  WWAIT(6, 0); MFMA4(hA, 4, 0); WLOAD(r0[0], q0, 0);   WLOAD(r1[0], q1, 0);
  WWAIT(6, 1); MFMA4(hA, 5, 1); WLOAD(r0[1], q0, 64);  WLOAD(r1[1], q1, 64);
  WWAIT(6, 2); MFMA4(hA, 6, 2); WLOAD(r0[2], q0, 128); WLOAD(r1[2], q1, 128);
  WWAIT(6, 3); MFMA4(hA, 7, 3); WLOAD(r0[3], q0, 192); WLOAD(r1[3], q1, 192);

  epilogue_store(acc, hB, b0A, b0B, wv, l16, lk8);   // reg-only epilogue
  __syncthreads();

#pragma unroll
  for (int mt = 0; mt < 4; ++mt)
#pragma unroll
    for (int nt = 0; nt < 2; ++nt)
      acc[mt][nt] = (f32x4){0.f, 0.f, 0.f, 0.f};

  // ---- gemm1 ----
  WWAIT(6, 0); MFMA4(hB, 0, 0); WLOAD(r0[0], q0, 256); WLOAD(r1[0], q1, 256);
  WWAIT(6, 1); MFMA4(hB, 1, 1); WLOAD(r0[1], q0, 320); WLOAD(r1[1], q1, 320);
  WWAIT(6, 2); MFMA4(hB, 2, 2); WLOAD(r0[2], q0, 384); WLOAD(r1[2], q1, 384);
  WWAIT(6, 3); MFMA4(hB, 3, 3); WLOAD(r0[3], q0, 448); WLOAD(r1[3], q1, 448);
  WWAIT(6, 0); MFMA4(hB, 4, 0);
  WWAIT(4, 1); MFMA4(hB, 5, 1);
  WWAIT(2, 2); MFMA4(hB, 6, 2);
  WWAIT(0, 3); MFMA4(hB, 7, 3);

  epilogue_store(acc, hA, b1A, b1B, wv, l16, lk8);
  __syncthreads();

  // ---- output layer via MFMA: D = Wo(3x256, zero-pad to 16) @ h2^T ----
  if (wv < 4) {                                   // wave wv owns points wv*16..+15
    f32x4 oacc = (f32x4){0.f, 0.f, 0.f, 0.f};
#pragma unroll
    for (int kk = 0; kk < 8; ++kk) {
      const int k = kk * 32 + lk8 * 8;
      const short8 wo = *(const short8*)&g_Wo[l16 * CCH + k];
      const short8 hb = *(const short8*)&hA[wv * 16 + l16][k];
      oacc = __builtin_amdgcn_mfma_f32_16x16x32_bf16(wo, hb, oacc, 0, 0, 0);
    }
    if (lk8 == 0) {
      const long pt = n0 + wv * 16 + l16;
#pragma unroll
      for (int i = 0; i < 3; ++i)
        out[pt * 3 + i] = 1.f / (1.f + __expf(-(oacc[i] + b_out[i])));
    }
  }
}

extern "C" void kernel_launch(void* const* d_in, const int* in_sizes, int n_in,
                              void* d_out, int out_size, void* d_ws, size_t ws_size,
                              hipStream_t stream) {
  const float* uv    = (const float*)d_in[0];
  const float* W_in  = (const float*)d_in[1];
  const float* b_in  = (const float*)d_in[2];
  const float* W_h0  = (const float*)d_in[3];
  const float* b_h0  = (const float*)d_in[4];
  const float* W_h1  = (const float*)d_in[5];
  const float* b_h1  = (const float*)d_in[6];
  const float* W_out = (const float*)d_in[7];
  const float* b_out = (const float*)d_in[8];

  const int N = in_sizes[0] / 2;                    // 524288

  transpose_w<<<dim3(8, 8, 2), dim3(32, 8), 0, stream>>>(W_h0, W_h1);
  prep_wo<<<1, CCH, 0, stream>>>(W_out);
  nerf_fused<<<dim3(N / MT), dim3(TPB), 0, stream>>>(
      uv, W_in, b_in, b_h0, b_h1, b_out, (float*)d_out);
}

// Round 13
// 417.880 us; speedup vs baseline: 1.5326x; 1.0003x over previous
//
#include <hip/hip_runtime.h>
#include <hip/hip_bf16.h>
#include <math.h>

#define CCH 256      // channels
#define MT  64       // points per block
#define ROWE 264     // padded LDS row (bf16): 528 B stride
#define TPB 512

typedef __attribute__((ext_vector_type(8))) short short8;
typedef __attribute__((ext_vector_type(4))) float f32x4;
typedef __attribute__((ext_vector_type(2))) unsigned int uint2v;

// Module-scope device scratch: transposed bf16 weights.
__device__ unsigned short g_T0[CCH * CCH];   // T0[n*256+k] = bf16(W_h0[k][n])
__device__ unsigned short g_T1[CCH * CCH];   // T1[n*256+k] = bf16(W_h1[k][n])
__device__ unsigned short g_Wo[16 * CCH];    // Wo[j][k] = bf16(W_out[k][j]), j<3 else 0

__device__ __forceinline__ unsigned short f2bf(float f) {
  unsigned u = __float_as_uint(f);
  u += 0x7fffu + ((u >> 16) & 1u);   // RNE
  return (unsigned short)(u >> 16);
}
__device__ __forceinline__ unsigned cvtpk(float lo, float hi) {
  unsigned r;
  asm("v_cvt_pk_bf16_f32 %0, %1, %2" : "=v"(r) : "v"(lo), "v"(hi));
  return r;
}

__global__ void transpose_w(const float* __restrict__ W0,
                            const float* __restrict__ W1) {
  __shared__ float tile[32][33];
  const float* src = blockIdx.z ? W1 : W0;
  unsigned short* dst = blockIdx.z ? g_T1 : g_T0;
  const int tx = threadIdx.x, ty = threadIdx.y;       // 32 x 8
  const int k0 = blockIdx.y * 32, n0 = blockIdx.x * 32;
#pragma unroll
  for (int r = 0; r < 4; ++r)
    tile[ty + r * 8][tx] = src[(k0 + ty + r * 8) * CCH + n0 + tx];
  __syncthreads();
#pragma unroll
  for (int r = 0; r < 4; ++r) {
    const int n = n0 + ty + r * 8;
    dst[n * CCH + k0 + tx] = f2bf(tile[tx][ty + r * 8]);
  }
}

__global__ void prep_wo(const float* __restrict__ W_out) {
  const int k = threadIdx.x;   // 256 threads
#pragma unroll
  for (int j = 0; j < 16; ++j)
    g_Wo[j * CCH + k] = (j < 3) ? f2bf(W_out[k * 3 + j]) : (unsigned short)0;
}

// MFMA main loop (swapped operands: D = W^T h^T). Weights loaded in-loop
// from L2 (imm-offset folded); 6 waves/SIMD of TLP hide the latency.
__device__ __forceinline__ void mfma_gemm(
    const unsigned short (*__restrict__ src)[ROWE],
    const unsigned short* __restrict__ Wt,
    f32x4 acc[4][2], int wv, int l16, int lk8) {
#pragma unroll
  for (int mt = 0; mt < 4; ++mt)
#pragma unroll
    for (int nt = 0; nt < 2; ++nt)
      acc[mt][nt] = (f32x4){0.f, 0.f, 0.f, 0.f};

  const unsigned short* w0p = &Wt[(wv * 32 + l16) * CCH + lk8 * 8];
  const unsigned short* w1p = w0p + 16 * CCH;
  const unsigned short* a0p = &src[l16][lk8 * 8];

#pragma unroll
  for (int kk = 0; kk < 8; ++kk) {
    const int k = kk * 32;
    const short8 w0 = *(const short8*)&w0p[k];
    const short8 w1 = *(const short8*)&w1p[k];
#pragma unroll
    for (int mt = 0; mt < 4; ++mt) {
      const short8 a = *(const short8*)&a0p[mt * 16 * ROWE + k];
      acc[mt][0] = __builtin_amdgcn_mfma_f32_16x16x32_bf16(w0, a, acc[mt][0], 0, 0, 0);
      acc[mt][1] = __builtin_amdgcn_mfma_f32_16x16x32_bf16(w1, a, acc[mt][1], 0, 0, 0);
    }
  }
}

// bias + relu + bf16 pack; lane holds 4 consecutive channels of one point.
// Writes IN-PLACE into the same buffer the gemm just read (post-barrier).
__device__ __forceinline__ void epilogue_store(
    const f32x4 acc[4][2], unsigned short (*__restrict__ dst)[ROWE],
    const float* __restrict__ bias, int wv, int l16, int lk8) {
#pragma unroll
  for (int nt = 0; nt < 2; ++nt) {
    const int ch0 = wv * 32 + nt * 16 + lk8 * 4;
    const f32x4 bv = *(const f32x4*)&bias[ch0];
#pragma unroll
    for (int mt = 0; mt < 4; ++mt) {
      uint2v pk;
      pk[0] = cvtpk(fmaxf(acc[mt][nt][0] + bv[0], 0.f),
                    fmaxf(acc[mt][nt][1] + bv[1], 0.f));
      pk[1] = cvtpk(fmaxf(acc[mt][nt][2] + bv[2], 0.f),
                    fmaxf(acc[mt][nt][3] + bv[3], 0.f));
      *(uint2v*)&dst[mt * 16 + l16][ch0] = pk;   // 8B aligned
    }
  }
}

__global__ __launch_bounds__(TPB, 6) void nerf_fused(
    const float* __restrict__ uv,
    const float* __restrict__ W_in, const float* __restrict__ b_in,
    const float* __restrict__ b_h0, const float* __restrict__ b_h1,
    const float* __restrict__ b_out,
    float* __restrict__ out) {
  __shared__ unsigned short hA[MT][ROWE];   // single buffer, updated in place

  const int tid = threadIdx.x;
  const long n0 = (long)blockIdx.x * MT;
  const int wv = tid >> 6, ln = tid & 63;
  const int l16 = ln & 15, lk8 = ln >> 4;

  { // ---- layer 0: enc=[cos u, cos v, sin u, sin v] -> relu(enc@W_in+b_in)
    const int p = tid >> 3;
    const int t7 = tid & 7;
    const float u = uv[(n0 + p) * 2 + 0];
    const float v = uv[(n0 + p) * 2 + 1];
    const float e0 = __cosf(u), e1 = __cosf(v), e2 = __sinf(u), e3 = __sinf(v);
#pragma unroll
    for (int j = 0; j < 8; ++j) {
      const int c = t7 * 4 + j * 32;
      const f32x4 w0 = *(const f32x4*)&W_in[0 * CCH + c];
      const f32x4 w1 = *(const f32x4*)&W_in[1 * CCH + c];
      const f32x4 w2 = *(const f32x4*)&W_in[2 * CCH + c];
      const f32x4 w3 = *(const f32x4*)&W_in[3 * CCH + c];
      const f32x4 bb = *(const f32x4*)&b_in[c];
      float x[4];
#pragma unroll
      for (int i = 0; i < 4; ++i)
        x[i] = fmaxf(bb[i] + e0 * w0[i] + e1 * w1[i] + e2 * w2[i] + e3 * w3[i], 0.f);
      uint2v pk;
      pk[0] = cvtpk(x[0], x[1]);
      pk[1] = cvtpk(x[2], x[3]);
      *(uint2v*)&hA[p][c] = pk;
    }
  }
  __syncthreads();

  f32x4 acc[4][2];

  // ---- gemm0: read hA fully, then overwrite in place ----
  mfma_gemm(hA, g_T0, acc, wv, l16, lk8);
  __syncthreads();                               // all reads of hA complete
  epilogue_store(acc, hA, b_h0, wv, l16, lk8);
  __syncthreads();                               // all writes complete

  // ---- gemm1 ----
  mfma_gemm(hA, g_T1, acc, wv, l16, lk8);
  __syncthreads();
  epilogue_store(acc, hA, b_h1, wv, l16, lk8);
  __syncthreads();

  // ---- output layer via MFMA: D = Wo(3x256, zero-pad to 16) @ h2^T ----
  if (wv < 4) {                                  // wave wv owns points wv*16..+15
    f32x4 oacc = (f32x4){0.f, 0.f, 0.f, 0.f};
#pragma unroll
    for (int kk = 0; kk < 8; ++kk) {
      const int k = kk * 32 + lk8 * 8;
      const short8 wo = *(const short8*)&g_Wo[l16 * CCH + k];
      const short8 hb = *(const short8*)&hA[wv * 16 + l16][k];
      oacc = __builtin_amdgcn_mfma_f32_16x16x32_bf16(wo, hb, oacc, 0, 0, 0);
    }
    // D: col=l16=point, row=lk8*4+i=output j; only lk8==0, j<3 are real
    if (lk8 == 0) {
      const long pt = n0 + wv * 16 + l16;
#pragma unroll
      for (int i = 0; i < 3; ++i)
        out[pt * 3 + i] = 1.f / (1.f + __expf(-(oacc[i] + b_out[i])));
    }
  }
}

extern "C" void kernel_launch(void* const* d_in, const int* in_sizes, int n_in,
                              void* d_out, int out_size, void* d_ws, size_t ws_size,
                              hipStream_t stream) {
  const float* uv    = (const float*)d_in[0];
  const float* W_in  = (const float*)d_in[1];
  const float* b_in  = (const float*)d_in[2];
  const float* W_h0  = (const float*)d_in[3];
  const float* b_h0  = (const float*)d_in[4];
  const float* W_h1  = (const float*)d_in[5];
  const float* b_h1  = (const float*)d_in[6];
  const float* W_out = (const float*)d_in[7];
  const float* b_out = (const float*)d_in[8];

  const int N = in_sizes[0] / 2;                    // 524288

  transpose_w<<<dim3(8, 8, 2), dim3(32, 8), 0, stream>>>(W_h0, W_h1);
  prep_wo<<<1, CCH, 0, stream>>>(W_out);
  nerf_fused<<<dim3(N / MT), dim3(TPB), 0, stream>>>(
      uv, W_in, b_in, b_h0, b_h1, b_out, (float*)d_out);
}